// Round 1
// baseline (2749.019 us; speedup 1.0000x reference)
//
#include <hip/hip_runtime.h>

// ---------------------------------------------------------------------------
// VoxMLP: trilinear(grid value+grad) gather + annealed pos-enc + 5-layer MLP
// + Rodrigues rotation epilogue.
// Round 1: correctness-first scalar-FMA design, structured for later MFMA swap.
//   block = 256 threads (4 waves) = 64 points; wave w computes units
//   [32w, 32w+32); lane = point. Activations in LDS [unit][point] (bf16),
//   weights wave-uniform -> SGPR loads.
// ---------------------------------------------------------------------------

__device__ __forceinline__ float bf2f(unsigned short u) {
    union { float f; unsigned int i; } v; v.i = ((unsigned int)u) << 16; return v.f;
}
__device__ __forceinline__ unsigned short f2bf(float f) {
    union { float f; unsigned int i; } v; v.f = f;
    unsigned int x = v.i;
    return (unsigned short)((x + 0x7fffu + ((x >> 16) & 1u)) >> 16);
}

__device__ __forceinline__ float gv(const float* __restrict__ g, int i, int j, int k) {
    return g[(i * 256 + j) * 256 + k];
}

// acc[k] += src[j][lane] * W[j*128 + k]  (W already offset by i0)
__device__ __forceinline__ void gemm_f32(float acc[32], const float* __restrict__ src,
                                         const float* __restrict__ Wbase, int K, int lane)
{
    for (int j = 0; j < K; ++j) {
        const float hj = src[j * 64 + lane];
        const float* wr = Wbase + j * 128;
        #pragma unroll
        for (int k = 0; k < 32; ++k) acc[k] = fmaf(hj, wr[k], acc[k]);
    }
}
__device__ __forceinline__ void gemm_bf(float acc[32], const unsigned short* __restrict__ src,
                                        const float* __restrict__ Wbase, int K, int lane)
{
    for (int j = 0; j < K; ++j) {
        const float hj = bf2f(src[j * 64 + lane]);
        const float* wr = Wbase + j * 128;
        #pragma unroll
        for (int k = 0; k < 32; ++k) acc[k] = fmaf(hj, wr[k], acc[k]);
    }
}

__global__ __launch_bounds__(256, 3) void voxmlp(
    const float* __restrict__ x, const float* __restrict__ grid,
    const float* __restrict__ w0, const float* __restrict__ b0,
    const float* __restrict__ w1, const float* __restrict__ b1,
    const float* __restrict__ w2, const float* __restrict__ b2,
    const float* __restrict__ w3, const float* __restrict__ b3,
    const float* __restrict__ wo, const float* __restrict__ bo,
    float* __restrict__ out, int B)
{
    __shared__ float feats[63 * 64];          // [feat][point], fp32 (16.1 KB)
    __shared__ unsigned short hA[128 * 64];   // [unit][point], bf16 (16 KB)
    __shared__ unsigned short hB[128 * 64];   // (16 KB)  total 48.9 KB -> 3 blk/CU

    const int t = threadIdx.x;
    const int lane = t & 63;
    const int i0 = __builtin_amdgcn_readfirstlane((t >> 6) * 32);  // wave's unit base

    float ret0 = 0.f, c1 = 0.f, c2 = 0.f, c3 = 0.f;  // live only for t<64

    // ---- Phase 1 (wave 0 only): gather + trilinear + features -------------
    if (t < 64) {
        const int pid = blockIdx.x * 64 + t;
        const float px = x[pid * 3 + 0];
        const float py = x[pid * 3 + 1];
        const float pz = x[pid * 3 + 2];

        // NDELTA = 2/255 ; 1/NDELTA = 127.5 ; 1/(2*NDELTA) = 63.75
        const float fx = (px + 1.0f) * 127.5f;
        const float fy = (py + 1.0f) * 127.5f;
        const float fz = (pz + 1.0f) * 127.5f;
        const float fx0 = floorf(fx), fy0 = floorf(fy), fz0 = floorf(fz);
        const float xd = fx - fx0, yd = fy - fy0, zd = fz - fz0;
        int ix0 = min(max((int)fx0, 0), 255);
        int iy0 = min(max((int)fy0, 0), 255);
        int iz0 = min(max((int)fz0, 0), 255);
        int ix1 = min(ix0 + 1, 255);
        int iy1 = min(iy0 + 1, 255);
        int iz1 = min(iz0 + 1, 255);

        #pragma unroll
        for (int c = 0; c < 8; ++c) {
            const int i = (c & 4) ? ix1 : ix0;
            const int j = (c & 2) ? iy1 : iy0;
            const int k = (c & 1) ? iz1 : iz0;
            const float wgt = ((c & 4) ? xd : 1.0f - xd) *
                              ((c & 2) ? yd : 1.0f - yd) *
                              ((c & 1) ? zd : 1.0f - zd);
            const float v  = gv(grid, i, j, k);
            // edge-padded central differences == index-clamped
            const float gx = (gv(grid, min(i + 1, 255), j, k) - gv(grid, max(i - 1, 0), j, k)) * 63.75f;
            const float gy = (gv(grid, i, min(j + 1, 255), k) - gv(grid, i, max(j - 1, 0), k)) * 63.75f;
            const float gz = (gv(grid, i, j, min(k + 1, 255)) - gv(grid, i, j, max(k - 1, 0))) * 63.75f;
            ret0 = fmaf(wgt, v,  ret0);
            c1   = fmaf(wgt, gx, c1);
            c2   = fmaf(wgt, gy, c2);
            c3   = fmaf(wgt, gz, c3);
        }

        // features: [x,y,z] then per band b: sin(2^b*{x,y,z}), sin(2^b*{x,y,z}+pi/2)
        // (alpha=10 -> all band weights == 1)
        feats[0 * 64 + t] = px;
        feats[1 * 64 + t] = py;
        feats[2 * 64 + t] = pz;
        const float PIH = 1.5707963267948966f;
        float s = 1.0f;
        for (int b = 0; b < 10; ++b) {
            const float vx = px * s, vy = py * s, vz = pz * s;
            const int base = 3 + b * 6;
            feats[(base + 0) * 64 + t] = sinf(vx);
            feats[(base + 1) * 64 + t] = sinf(vy);
            feats[(base + 2) * 64 + t] = sinf(vz);
            feats[(base + 3) * 64 + t] = sinf(vx + PIH);
            feats[(base + 4) * 64 + t] = sinf(vy + PIH);
            feats[(base + 5) * 64 + t] = sinf(vz + PIH);
            s *= 2.0f;
        }
    }
    __syncthreads();

    float acc[32];

    // ---- L0: feats(63) -> 128, relu --------------------------------------
    #pragma unroll
    for (int k = 0; k < 32; ++k) acc[k] = b0[i0 + k];
    gemm_f32(acc, feats, w0 + i0, 63, lane);
    #pragma unroll
    for (int k = 0; k < 32; ++k) hA[(i0 + k) * 64 + lane] = f2bf(fmaxf(acc[k], 0.0f));
    __syncthreads();

    // ---- L1: 128 -> 128, relu --------------------------------------------
    #pragma unroll
    for (int k = 0; k < 32; ++k) acc[k] = b1[i0 + k];
    gemm_bf(acc, hA, w1 + i0, 128, lane);
    #pragma unroll
    for (int k = 0; k < 32; ++k) hB[(i0 + k) * 64 + lane] = f2bf(fmaxf(acc[k], 0.0f));
    __syncthreads();

    // ---- L2: 128 -> 128, relu --------------------------------------------
    #pragma unroll
    for (int k = 0; k < 32; ++k) acc[k] = b2[i0 + k];
    gemm_bf(acc, hB, w2 + i0, 128, lane);
    #pragma unroll
    for (int k = 0; k < 32; ++k) hA[(i0 + k) * 64 + lane] = f2bf(fmaxf(acc[k], 0.0f));
    __syncthreads();

    // ---- L3: concat(h(128), feats(63)) -> 128, relu ----------------------
    #pragma unroll
    for (int k = 0; k < 32; ++k) acc[k] = b3[i0 + k];
    gemm_bf (acc, hA, w3 + i0, 128, lane);                 // rows 0..127: h
    gemm_f32(acc, feats, w3 + 128 * 128 + i0, 63, lane);   // rows 128..190: feats
    #pragma unroll
    for (int k = 0; k < 32; ++k) hB[(i0 + k) * 64 + lane] = f2bf(fmaxf(acc[k], 0.0f));
    __syncthreads();

    // ---- Output layer (128 -> 3) + Rodrigues epilogue (wave 0) -----------
    if (t < 64) {
        const int pid = blockIdx.x * 64 + t;
        float r0 = bo[0], r1 = bo[1], r2 = bo[2];
        for (int j = 0; j < 128; ++j) {
            const float hj = bf2f(hB[j * 64 + t]);
            r0 = fmaf(hj, wo[j * 3 + 0], r0);
            r1 = fmaf(hj, wo[j * 3 + 1], r1);
            r2 = fmaf(hj, wo[j * 3 + 2], r2);
        }
        const float theta = sqrtf(fmaf(r0, r0, fmaf(r1, r1, r2 * r2)) + 1e-12f);
        const float e0 = r0 / theta, e1 = r1 / theta, e2 = r2 / theta;
        const float a = sqrtf(fmaf(c1, c1, fmaf(c2, c2, c3 * c3)) + 1e-12f);
        const float v0 = c1 / a, v1 = c2 / a, v2 = c3 / a;
        const float ct = cosf(theta), st = sinf(theta);
        const float cx = e1 * v2 - e2 * v1;
        const float cy = e2 * v0 - e0 * v2;
        const float cz = e0 * v1 - e1 * v0;
        const float dd = e0 * v0 + e1 * v1 + e2 * v2;
        const float om = (1.0f - ct) * dd;
        const float rr0 = a * (ct * v0 + st * cx + om * e0);
        const float rr1 = a * (ct * v1 + st * cy + om * e1);
        const float rr2 = a * (ct * v2 + st * cz + om * e2);

        out[pid] = ret0;                       // output 0: (B,1)
        out[B + pid * 3 + 0] = c1;             // output 1: (B,3)
        out[B + pid * 3 + 1] = c2;
        out[B + pid * 3 + 2] = c3;
        out[4 * B + pid * 3 + 0] = rr0;        // output 2: (B,3)
        out[4 * B + pid * 3 + 1] = rr1;
        out[4 * B + pid * 3 + 2] = rr2;
    }
}

extern "C" void kernel_launch(void* const* d_in, const int* in_sizes, int n_in,
                              void* d_out, int out_size, void* d_ws, size_t ws_size,
                              hipStream_t stream)
{
    const float* x    = (const float*)d_in[0];
    const float* grid = (const float*)d_in[1];
    const float* w0   = (const float*)d_in[2];
    const float* b0   = (const float*)d_in[3];
    const float* w1   = (const float*)d_in[4];
    const float* b1   = (const float*)d_in[5];
    const float* w2   = (const float*)d_in[6];
    const float* b2   = (const float*)d_in[7];
    const float* w3   = (const float*)d_in[8];
    const float* b3   = (const float*)d_in[9];
    const float* wo   = (const float*)d_in[10];
    const float* bo   = (const float*)d_in[11];
    float* out = (float*)d_out;

    const int B = in_sizes[0] / 3;   // 1,048,576
    const int nblocks = B / 64;      // 16,384
    voxmlp<<<nblocks, 256, 0, stream>>>(x, grid, w0, b0, w1, b1, w2, b2, w3, b3, wo, bo, out, B);
}

// Round 3
// 492.612 us; speedup vs baseline: 5.5805x; 5.5805x over previous
//
#include <hip/hip_runtime.h>

// ---------------------------------------------------------------------------
// VoxMLP round 3: MFMA bf16 MLP, cross-lane-free phase 1.
//   Pre-kernel: swizzle w0..w3,wo into bf16 MFMA A-operand layout in d_ws
//     (weights are src0 of mfma: C[unit][point] = W.A * act.B).
//   Main: 256 thr = 4 independent waves x 32 points, no block barriers.
//     Lanes 0..31: full 8-corner gather+trilinear for point (lane&31); writes
//       out0/out1 directly (R1-proven code path), stashes c1..c3 in LDS pad.
//     Lanes 32..63: all 63 pos-enc features for point (lane&31) -> LDS bf16.
//     MLP: v_mfma_f32_16x16x32_bf16, A=weights (A[m=lane&15][k=quad*8+j]),
//       B=activations (B[k=quad*8+j][n=lane&15]), C/D row=quad*4+r col=lane&15.
// ---------------------------------------------------------------------------

typedef __attribute__((ext_vector_type(8))) short bf8;   // 8 bf16 = 4 VGPR
typedef __attribute__((ext_vector_type(4))) float f4;

__device__ __forceinline__ float bf2f(unsigned short u) {
    union { float f; unsigned int i; } v; v.i = ((unsigned int)u) << 16; return v.f;
}
__device__ __forceinline__ unsigned short f2bf(float f) {
    union { float f; unsigned int i; } v; v.f = f;
    unsigned int x = v.i;
    return (unsigned short)((x + 0x7fffu + ((x >> 16) & 1u)) >> 16);
}
__device__ __forceinline__ float gv(const float* __restrict__ g, int i, int j, int k) {
    return g[(i * 256 + j) * 256 + k];
}

// ---- d_ws layout (bf16 elements) ----
// L0: K=63->64 (KT=2), N=128 (NT=8): [0, 8192)
// L1: K=128 (KT=4):                  [8192, 24576)
// L2:                                [24576, 40960)
// L3: K=191->192 (KT=6):             [40960, 65536)
// out: K=128 (KT=4), N=3 (NT=1):     [65536, 67584)
#define WS_TOTAL 67584

__global__ __launch_bounds__(256) void swizzle_w(
    const float* __restrict__ w0, const float* __restrict__ w1,
    const float* __restrict__ w2, const float* __restrict__ w3,
    const float* __restrict__ wo, unsigned short* __restrict__ ws)
{
    int idx = blockIdx.x * 256 + threadIdx.x;
    if (idx >= WS_TOTAL) return;
    const float* src; int base, NT, Kact, Nact, ld;
    if (idx < 8192)       { src = w0; base = 0;     NT = 8; Kact = 63;  Nact = 128; ld = 128; }
    else if (idx < 24576) { src = w1; base = 8192;  NT = 8; Kact = 128; Nact = 128; ld = 128; }
    else if (idx < 40960) { src = w2; base = 24576; NT = 8; Kact = 128; Nact = 128; ld = 128; }
    else if (idx < 65536) { src = w3; base = 40960; NT = 8; Kact = 191; Nact = 128; ld = 128; }
    else                  { src = wo; base = 65536; NT = 1; Kact = 128; Nact = 3;   ld = 3;   }
    int local = idx - base;
    int j = local & 7;
    int lane = (local >> 3) & 63;
    int chunk = local >> 9;              // = kt*NT + nt
    int nt = chunk % NT, kt = chunk / NT;
    int k = kt * 32 + ((lane >> 4) << 3) + j;   // A-op: k = quad*8 + j (+32*kt)
    int n = nt * 16 + (lane & 15);              // A-op: m(unit) = lane&15 (+16*nt)
    float v = (k < Kact && n < Nact) ? src[k * ld + n] : 0.0f;
    ws[idx] = f2bf(v);
}

// per-wave LDS: bufH 32x136 bf16 (8704 B), fbuf 32x72 bf16 (4608 B) = 13312 B
// fbuf row: shorts [0..63] = features (+zero pad at 63); shorts [64..69] =
// 3 fp32 (c1,c2,c3) stash for the epilogue (byte offset 128, 16B-aligned).
#define WV_SH 6656
#define HSTRIDE 136
#define FSTRIDE 72

__global__ __launch_bounds__(256, 3) void voxmlp(
    const float* __restrict__ x, const float* __restrict__ grid,
    const unsigned short* __restrict__ ws,
    const float* __restrict__ b0, const float* __restrict__ b1,
    const float* __restrict__ b2, const float* __restrict__ b3,
    const float* __restrict__ bo,
    float* __restrict__ out, int B)
{
    __shared__ unsigned short smem[WV_SH * 4];   // 53248 B -> 3 blocks/CU

    const int lane = threadIdx.x & 63;
    const int wave = threadIdx.x >> 6;
    const int quad = lane >> 4;
    const int lm   = lane & 15;
    unsigned short* bufH = smem + wave * WV_SH;
    unsigned short* fbuf = bufH + 32 * HSTRIDE;

    const int pbase = blockIdx.x * 128 + wave * 32;   // wave's first point

    // ================= Phase 1 ============================================
    const int p2   = lane & 31;          // point within wave
    const int role = lane >> 5;          // 0: gather half, 1: feature half
    const int pid  = pbase + p2;

    const float px = x[pid * 3 + 0];
    const float py = x[pid * 3 + 1];
    const float pz = x[pid * 3 + 2];

    if (role == 0) {
        // ---- full 8-corner gather + trilinear (R1-proven, one lane/point) --
        const float fx = (px + 1.0f) * 127.5f;
        const float fy = (py + 1.0f) * 127.5f;
        const float fz = (pz + 1.0f) * 127.5f;
        const float fx0 = floorf(fx), fy0 = floorf(fy), fz0 = floorf(fz);
        const float xd = fx - fx0, yd = fy - fy0, zd = fz - fz0;
        const int ix0 = min(max((int)fx0, 0), 255);
        const int iy0 = min(max((int)fy0, 0), 255);
        const int iz0 = min(max((int)fz0, 0), 255);
        const int ix1 = min(ix0 + 1, 255);
        const int iy1 = min(iy0 + 1, 255);
        const int iz1 = min(iz0 + 1, 255);

        float ret0 = 0.f, c1 = 0.f, c2 = 0.f, c3 = 0.f;
        #pragma unroll
        for (int c = 0; c < 8; ++c) {
            const int i = (c & 4) ? ix1 : ix0;
            const int j = (c & 2) ? iy1 : iy0;
            const int k = (c & 1) ? iz1 : iz0;
            const float wgt = ((c & 4) ? xd : 1.0f - xd) *
                              ((c & 2) ? yd : 1.0f - yd) *
                              ((c & 1) ? zd : 1.0f - zd);
            const float v  = gv(grid, i, j, k);
            const float gx = (gv(grid, min(i + 1, 255), j, k) - gv(grid, max(i - 1, 0), j, k)) * 63.75f;
            const float gy = (gv(grid, i, min(j + 1, 255), k) - gv(grid, i, max(j - 1, 0), k)) * 63.75f;
            const float gz = (gv(grid, i, j, min(k + 1, 255)) - gv(grid, i, j, max(k - 1, 0))) * 63.75f;
            ret0 = fmaf(wgt, v,  ret0);
            c1   = fmaf(wgt, gx, c1);
            c2   = fmaf(wgt, gy, c2);
            c3   = fmaf(wgt, gz, c3);
        }
        out[pid] = ret0;                       // output 0: (B,1)
        out[B + pid * 3 + 0] = c1;             // output 1: (B,3)
        out[B + pid * 3 + 1] = c2;
        out[B + pid * 3 + 2] = c3;
        float* cst = (float*)(fbuf + p2 * FSTRIDE + 64);   // LDS stash for epilogue
        cst[0] = c1; cst[1] = c2; cst[2] = c3;
    } else {
        // ---- all 63 features for this point -------------------------------
        unsigned short* fb = fbuf + p2 * FSTRIDE;
        fb[0] = f2bf(px); fb[1] = f2bf(py); fb[2] = f2bf(pz);
        fb[63] = 0;                                         // K=64 zero pad
        float s = 1.0f;
        #pragma unroll
        for (int b = 0; b < 10; ++b) {
            const int base = 3 + b * 6;
            float sv, cv;
            __sincosf(px * s, &sv, &cv); fb[base + 0] = f2bf(sv); fb[base + 3] = f2bf(cv);
            __sincosf(py * s, &sv, &cv); fb[base + 1] = f2bf(sv); fb[base + 4] = f2bf(cv);
            __sincosf(pz * s, &sv, &cv); fb[base + 2] = f2bf(sv); fb[base + 5] = f2bf(cv);
            s *= 2.0f;
        }
    }
    // no barrier needed: producer and consumer are the same wave (in-order DS)

    // ================= MLP via MFMA ========================================
    bf8 af[2][6];
    const int arow0 = lm * HSTRIDE + quad * 8;          // bufH A-frag base (pt=0)
    const int frow0 = lm * FSTRIDE + quad * 8;

    auto store_tile = [&](f4 acc, int pt, int ut) {
        unsigned int lo = (unsigned int)f2bf(fmaxf(acc[0], 0.f))
                        | ((unsigned int)f2bf(fmaxf(acc[1], 0.f)) << 16);
        unsigned int hi = (unsigned int)f2bf(fmaxf(acc[2], 0.f))
                        | ((unsigned int)f2bf(fmaxf(acc[3], 0.f)) << 16);
        uint2 pk; pk.x = lo; pk.y = hi;
        *(uint2*)(bufH + (pt * 16 + lm) * HSTRIDE + ut * 16 + quad * 4) = pk;
    };

    // ---- L0: fbuf(K=64) -> bufH ----
    #pragma unroll
    for (int pt = 0; pt < 2; ++pt)
        #pragma unroll
        for (int kt = 0; kt < 2; ++kt)
            af[pt][kt] = *(const bf8*)(fbuf + pt * 16 * FSTRIDE + frow0 + kt * 32);
    #pragma unroll
    for (int ut = 0; ut < 8; ++ut) {
        bf8 wf[2];
        #pragma unroll
        for (int kt = 0; kt < 2; ++kt)
            wf[kt] = *(const bf8*)(ws + 0 + (((kt * 8 + ut) * 64 + lane) << 3));
        const f4 bias = *(const f4*)(b0 + ut * 16 + quad * 4);
        #pragma unroll
        for (int pt = 0; pt < 2; ++pt) {
            f4 acc = bias;
            #pragma unroll
            for (int kt = 0; kt < 2; ++kt)
                acc = __builtin_amdgcn_mfma_f32_16x16x32_bf16(wf[kt], af[pt][kt], acc, 0, 0, 0);
            store_tile(acc, pt, ut);
        }
    }

    // ---- L1, L2: bufH(K=128) -> bufH ----
    #pragma unroll
    for (int layer = 0; layer < 2; ++layer) {
        const unsigned short* wsl = ws + (layer == 0 ? 8192 : 24576);
        const float* bias_p = (layer == 0) ? b1 : b2;
        #pragma unroll
        for (int pt = 0; pt < 2; ++pt)
            #pragma unroll
            for (int kt = 0; kt < 4; ++kt)
                af[pt][kt] = *(const bf8*)(bufH + pt * 16 * HSTRIDE + arow0 + kt * 32);
        #pragma unroll
        for (int ut = 0; ut < 8; ++ut) {
            bf8 wf[4];
            #pragma unroll
            for (int kt = 0; kt < 4; ++kt)
                wf[kt] = *(const bf8*)(wsl + (((kt * 8 + ut) * 64 + lane) << 3));
            const f4 bias = *(const f4*)(bias_p + ut * 16 + quad * 4);
            #pragma unroll
            for (int pt = 0; pt < 2; ++pt) {
                f4 acc = bias;
                #pragma unroll
                for (int kt = 0; kt < 4; ++kt)
                    acc = __builtin_amdgcn_mfma_f32_16x16x32_bf16(wf[kt], af[pt][kt], acc, 0, 0, 0);
                store_tile(acc, pt, ut);
            }
        }
    }

    // ---- L3: concat(bufH 128, fbuf 63) K=192 -> bufH ----
    #pragma unroll
    for (int pt = 0; pt < 2; ++pt) {
        #pragma unroll
        for (int kt = 0; kt < 4; ++kt)
            af[pt][kt] = *(const bf8*)(bufH + pt * 16 * HSTRIDE + arow0 + kt * 32);
        #pragma unroll
        for (int kk = 0; kk < 2; ++kk)
            af[pt][4 + kk] = *(const bf8*)(fbuf + pt * 16 * FSTRIDE + frow0 + kk * 32);
    }
    #pragma unroll
    for (int ut = 0; ut < 8; ++ut) {
        bf8 wf[6];
        #pragma unroll
        for (int kt = 0; kt < 6; ++kt)
            wf[kt] = *(const bf8*)(ws + 40960 + (((kt * 8 + ut) * 64 + lane) << 3));
        const f4 bias = *(const f4*)(b3 + ut * 16 + quad * 4);
        #pragma unroll
        for (int pt = 0; pt < 2; ++pt) {
            f4 acc = bias;
            #pragma unroll
            for (int kt = 0; kt < 6; ++kt)
                acc = __builtin_amdgcn_mfma_f32_16x16x32_bf16(wf[kt], af[pt][kt], acc, 0, 0, 0);
            store_tile(acc, pt, ut);
        }
    }

    // ---- output layer (K=128, N=3) + Rodrigues epilogue ----
    #pragma unroll
    for (int pt = 0; pt < 2; ++pt)
        #pragma unroll
        for (int kt = 0; kt < 4; ++kt)
            af[pt][kt] = *(const bf8*)(bufH + pt * 16 * HSTRIDE + arow0 + kt * 32);
    bf8 wf[4];
    #pragma unroll
    for (int kt = 0; kt < 4; ++kt)
        wf[kt] = *(const bf8*)(ws + 65536 + ((kt * 64 + lane) << 3));

    #pragma unroll
    for (int pt = 0; pt < 2; ++pt) {
        f4 acc;
        #pragma unroll
        for (int r = 0; r < 4; ++r) {
            const int u = quad * 4 + r;
            acc[r] = (u < 3) ? bo[u] : 0.0f;
        }
        #pragma unroll
        for (int kt = 0; kt < 4; ++kt)
            acc = __builtin_amdgcn_mfma_f32_16x16x32_bf16(wf[kt], af[pt][kt], acc, 0, 0, 0);

        const int pp = pt * 16 + lm;                       // point idx in wave
        const float* cst = (const float*)(fbuf + pp * FSTRIDE + 64);
        const float g1 = cst[0], g2 = cst[1], g3 = cst[2];
        const float r0 = acc[0], r1 = acc[1], r2 = acc[2];
        const float theta = sqrtf(fmaf(r0, r0, fmaf(r1, r1, r2 * r2)) + 1e-12f);
        const float e0 = r0 / theta, e1 = r1 / theta, e2 = r2 / theta;
        const float a = sqrtf(fmaf(g1, g1, fmaf(g2, g2, g3 * g3)) + 1e-12f);
        const float v0 = g1 / a, v1 = g2 / a, v2 = g3 / a;
        const float ct = cosf(theta), st = sinf(theta);
        const float cx = e1 * v2 - e2 * v1;
        const float cy = e2 * v0 - e0 * v2;
        const float cz = e0 * v1 - e1 * v0;
        const float om = (1.0f - ct) * (e0 * v0 + e1 * v1 + e2 * v2);
        if (quad == 0) {
            const int pid2 = pbase + pp;
            out[4 * B + pid2 * 3 + 0] = a * (ct * v0 + st * cx + om * e0);
            out[4 * B + pid2 * 3 + 1] = a * (ct * v1 + st * cy + om * e1);
            out[4 * B + pid2 * 3 + 2] = a * (ct * v2 + st * cz + om * e2);
        }
    }
}

extern "C" void kernel_launch(void* const* d_in, const int* in_sizes, int n_in,
                              void* d_out, int out_size, void* d_ws, size_t ws_size,
                              hipStream_t stream)
{
    const float* x    = (const float*)d_in[0];
    const float* grid = (const float*)d_in[1];
    const float* w0   = (const float*)d_in[2];
    const float* b0   = (const float*)d_in[3];
    const float* w1   = (const float*)d_in[4];
    const float* b1   = (const float*)d_in[5];
    const float* w2   = (const float*)d_in[6];
    const float* b2   = (const float*)d_in[7];
    const float* w3   = (const float*)d_in[8];
    const float* b3   = (const float*)d_in[9];
    const float* wo   = (const float*)d_in[10];
    const float* bo   = (const float*)d_in[11];
    float* out = (float*)d_out;
    unsigned short* ws = (unsigned short*)d_ws;

    const int B = in_sizes[0] / 3;        // 1,048,576
    swizzle_w<<<(WS_TOTAL + 255) / 256, 256, 0, stream>>>(w0, w1, w2, w3, wo, ws);
    voxmlp<<<B / 128, 256, 0, stream>>>(x, grid, ws, b0, b1, b2, b3, bo, out, B);
}

// Round 4
// 387.112 us; speedup vs baseline: 7.1014x; 1.2725x over previous
//
#include <hip/hip_runtime.h>

// ---------------------------------------------------------------------------
// VoxMLP round 4: precomputed bf16 data-grid gather + MFMA bf16 MLP.
//   swizzle_w : weights -> bf16 MFMA A-operand fragments in d_ws[0..67584)
//   make_dgrid: grid -> [v,gx,gy,gz] bf16x4 per voxel at d_ws+256KB (134 MB,
//               L3-resident) -- gather drops from 32 scattered fp32 loads to
//               8 aligned 8B loads per point.
//   voxmlp<FAST>: 256 thr = 4 waves x 32 points. Lanes 0..31 gather+trilinear
//     (out0/out1 + LDS stash), lanes 32..63 pos-enc features. MLP via
//     v_mfma_f32_16x16x32_bf16 (A=weights, B=activations, C=[unit][point]).
//     Raw s_barrier after phase1/layers phase-aligns waves so identical
//     weight-fragment loads hit L1.
//   FAST=false fallback (R3-proven 32-load gather) if ws_size too small.
// ---------------------------------------------------------------------------

typedef __attribute__((ext_vector_type(8))) short bf8;   // 8 bf16 = 4 VGPR
typedef __attribute__((ext_vector_type(4))) float f4;

__device__ __forceinline__ float bf2f(unsigned int u) {
    union { float f; unsigned int i; } v; v.i = u << 16; return v.f;
}
__device__ __forceinline__ unsigned short f2bf(float f) {
    union { float f; unsigned int i; } v; v.f = f;
    unsigned int x = v.i;
    return (unsigned short)((x + 0x7fffu + ((x >> 16) & 1u)) >> 16);
}
__device__ __forceinline__ float gv(const float* __restrict__ g, int i, int j, int k) {
    return g[(i * 256 + j) * 256 + k];
}

// ---- d_ws layout ----
// shorts [0, 67584): swizzled weights (L0,L1,L2,L3,out)
// bytes  [262144, 262144 + 16.7M*8): bf16x4 data grid
#define WS_TOTAL 67584
#define DG_OFF_SH 131072
#define WS_NEED (262144ull + 16777216ull * 8ull)

__global__ __launch_bounds__(256) void swizzle_w(
    const float* __restrict__ w0, const float* __restrict__ w1,
    const float* __restrict__ w2, const float* __restrict__ w3,
    const float* __restrict__ wo, unsigned short* __restrict__ ws)
{
    int idx = blockIdx.x * 256 + threadIdx.x;
    if (idx >= WS_TOTAL) return;
    const float* src; int base, NT, Kact, Nact, ld;
    if (idx < 8192)       { src = w0; base = 0;     NT = 8; Kact = 63;  Nact = 128; ld = 128; }
    else if (idx < 24576) { src = w1; base = 8192;  NT = 8; Kact = 128; Nact = 128; ld = 128; }
    else if (idx < 40960) { src = w2; base = 24576; NT = 8; Kact = 128; Nact = 128; ld = 128; }
    else if (idx < 65536) { src = w3; base = 40960; NT = 8; Kact = 191; Nact = 128; ld = 128; }
    else                  { src = wo; base = 65536; NT = 1; Kact = 128; Nact = 3;   ld = 3;   }
    int local = idx - base;
    int j = local & 7;
    int lane = (local >> 3) & 63;
    int chunk = local >> 9;              // = kt*NT + nt
    int nt = chunk % NT, kt = chunk / NT;
    int k = kt * 32 + ((lane >> 4) << 3) + j;   // A-op: k = quad*8 + j (+32*kt)
    int n = nt * 16 + (lane & 15);              // A-op: m(unit) = lane&15 (+16*nt)
    float v = (k < Kact && n < Nact) ? src[k * ld + n] : 0.0f;
    ws[idx] = f2bf(v);
}

// one thread = 4 voxels along z; 16384 blocks x 256 threads
__global__ __launch_bounds__(256) void make_dgrid(
    const float* __restrict__ g, unsigned short* __restrict__ dg)
{
    const int t  = blockIdx.x * 256 + threadIdx.x;       // [0, 2^22)
    const int k0 = (t & 63) << 2;
    const int j  = (t >> 6) & 255;
    const int i  = t >> 14;
    const float* row = g + (i * 256 + j) * 256;
    const f4 self = *(const f4*)(row + k0);
    const f4 xp = *(const f4*)(g + (min(i + 1, 255) * 256 + j) * 256 + k0);
    const f4 xm = *(const f4*)(g + (max(i - 1, 0)   * 256 + j) * 256 + k0);
    const f4 yp = *(const f4*)(g + (i * 256 + min(j + 1, 255)) * 256 + k0);
    const f4 ym = *(const f4*)(g + (i * 256 + max(j - 1, 0))   * 256 + k0);
    const float zlo = row[max(k0 - 1, 0)];        // == clamp value when k0==0
    const float zhi = row[min(k0 + 4, 255)];      // == clamp value when k0==252
    float zv[6] = {zlo, self[0], self[1], self[2], self[3], zhi};
    unsigned short o[16];
    #pragma unroll
    for (int q = 0; q < 4; ++q) {
        o[q * 4 + 0] = f2bf(self[q]);
        o[q * 4 + 1] = f2bf((xp[q] - xm[q]) * 63.75f);
        o[q * 4 + 2] = f2bf((yp[q] - ym[q]) * 63.75f);
        o[q * 4 + 3] = f2bf((zv[q + 2] - zv[q]) * 63.75f);
    }
    unsigned short* dst = dg + (size_t)(((i * 256 + j) * 256 + k0)) * 4;
    *(uint4*)(dst)     = *(const uint4*)(o);
    *(uint4*)(dst + 8) = *(const uint4*)(o + 8);
}

// per-wave LDS: bufH 32x136 bf16 (8704 B), fbuf 32x72 bf16 (4608 B)
// fbuf row: [0..63] features (+pad); [64..69] 3 fp32 c1..c3 stash.
#define WV_SH 6656
#define HSTRIDE 136
#define FSTRIDE 72

template<bool FAST>
__global__ __launch_bounds__(256, 3) void voxmlp(
    const float* __restrict__ x, const float* __restrict__ grid,
    const unsigned short* __restrict__ ws, const unsigned short* __restrict__ dg,
    const float* __restrict__ b0, const float* __restrict__ b1,
    const float* __restrict__ b2, const float* __restrict__ b3,
    const float* __restrict__ bo,
    float* __restrict__ out, int B)
{
    __shared__ unsigned short smem[WV_SH * 4];   // 53248 B -> 3 blocks/CU

    const int lane = threadIdx.x & 63;
    const int wave = threadIdx.x >> 6;
    const int quad = lane >> 4;
    const int lm   = lane & 15;
    unsigned short* bufH = smem + wave * WV_SH;
    unsigned short* fbuf = bufH + 32 * HSTRIDE;

    const int pbase = blockIdx.x * 128 + wave * 32;

    // ================= Phase 1 ============================================
    const int p2   = lane & 31;
    const int role = lane >> 5;
    const int pid  = pbase + p2;

    const float px = x[pid * 3 + 0];
    const float py = x[pid * 3 + 1];
    const float pz = x[pid * 3 + 2];

    if (role == 0) {
        const float fx = (px + 1.0f) * 127.5f;
        const float fy = (py + 1.0f) * 127.5f;
        const float fz = (pz + 1.0f) * 127.5f;
        const float fx0 = floorf(fx), fy0 = floorf(fy), fz0 = floorf(fz);
        const float xd = fx - fx0, yd = fy - fy0, zd = fz - fz0;
        const int ix0 = min(max((int)fx0, 0), 255);
        const int iy0 = min(max((int)fy0, 0), 255);
        const int iz0 = min(max((int)fz0, 0), 255);
        const int ix1 = min(ix0 + 1, 255);
        const int iy1 = min(iy0 + 1, 255);
        const int iz1 = min(iz0 + 1, 255);

        float ret0 = 0.f, c1 = 0.f, c2 = 0.f, c3 = 0.f;
        if (FAST) {
            #pragma unroll
            for (int c = 0; c < 8; ++c) {
                const int i = (c & 4) ? ix1 : ix0;
                const int j = (c & 2) ? iy1 : iy0;
                const int k = (c & 1) ? iz1 : iz0;
                const float wgt = ((c & 4) ? xd : 1.0f - xd) *
                                  ((c & 2) ? yd : 1.0f - yd) *
                                  ((c & 1) ? zd : 1.0f - zd);
                const uint2 w = *(const uint2*)(dg + (size_t)((i * 256 + j) * 256 + k) * 4);
                ret0 = fmaf(wgt, bf2f(w.x & 0xffffu), ret0);
                c1   = fmaf(wgt, bf2f(w.x >> 16),     c1);
                c2   = fmaf(wgt, bf2f(w.y & 0xffffu), c2);
                c3   = fmaf(wgt, bf2f(w.y >> 16),     c3);
            }
        } else {
            #pragma unroll
            for (int c = 0; c < 8; ++c) {
                const int i = (c & 4) ? ix1 : ix0;
                const int j = (c & 2) ? iy1 : iy0;
                const int k = (c & 1) ? iz1 : iz0;
                const float wgt = ((c & 4) ? xd : 1.0f - xd) *
                                  ((c & 2) ? yd : 1.0f - yd) *
                                  ((c & 1) ? zd : 1.0f - zd);
                const float v  = gv(grid, i, j, k);
                const float gx = (gv(grid, min(i + 1, 255), j, k) - gv(grid, max(i - 1, 0), j, k)) * 63.75f;
                const float gy = (gv(grid, i, min(j + 1, 255), k) - gv(grid, i, max(j - 1, 0), k)) * 63.75f;
                const float gz = (gv(grid, i, j, min(k + 1, 255)) - gv(grid, i, j, max(k - 1, 0))) * 63.75f;
                ret0 = fmaf(wgt, v,  ret0);
                c1   = fmaf(wgt, gx, c1);
                c2   = fmaf(wgt, gy, c2);
                c3   = fmaf(wgt, gz, c3);
            }
        }
        out[pid] = ret0;                       // output 0: (B,1)
        out[B + pid * 3 + 0] = c1;             // output 1: (B,3)
        out[B + pid * 3 + 1] = c2;
        out[B + pid * 3 + 2] = c3;
        float* cst = (float*)(fbuf + p2 * FSTRIDE + 64);
        cst[0] = c1; cst[1] = c2; cst[2] = c3;
    } else {
        unsigned short* fb = fbuf + p2 * FSTRIDE;
        fb[0] = f2bf(px); fb[1] = f2bf(py); fb[2] = f2bf(pz);
        fb[63] = 0;
        float s = 1.0f;
        #pragma unroll
        for (int b = 0; b < 10; ++b) {
            const int base = 3 + b * 6;
            float sv, cv;
            __sincosf(px * s, &sv, &cv); fb[base + 0] = f2bf(sv); fb[base + 3] = f2bf(cv);
            __sincosf(py * s, &sv, &cv); fb[base + 1] = f2bf(sv); fb[base + 4] = f2bf(cv);
            __sincosf(pz * s, &sv, &cv); fb[base + 2] = f2bf(sv); fb[base + 5] = f2bf(cv);
            s *= 2.0f;
        }
    }
    __builtin_amdgcn_s_barrier();   // phase-align the 4 waves (L1 weight reuse)

    // ================= MLP via MFMA ========================================
    bf8 af[2][6];
    const int arow0 = lm * HSTRIDE + quad * 8;
    const int frow0 = lm * FSTRIDE + quad * 8;

    auto store_tile = [&](f4 acc, int pt, int ut) {
        unsigned int lo = (unsigned int)f2bf(fmaxf(acc[0], 0.f))
                        | ((unsigned int)f2bf(fmaxf(acc[1], 0.f)) << 16);
        unsigned int hi = (unsigned int)f2bf(fmaxf(acc[2], 0.f))
                        | ((unsigned int)f2bf(fmaxf(acc[3], 0.f)) << 16);
        uint2 pk; pk.x = lo; pk.y = hi;
        *(uint2*)(bufH + (pt * 16 + lm) * HSTRIDE + ut * 16 + quad * 4) = pk;
    };

    // ---- L0: fbuf(K=64) -> bufH ----
    #pragma unroll
    for (int pt = 0; pt < 2; ++pt)
        #pragma unroll
        for (int kt = 0; kt < 2; ++kt)
            af[pt][kt] = *(const bf8*)(fbuf + pt * 16 * FSTRIDE + frow0 + kt * 32);
    #pragma unroll
    for (int ut = 0; ut < 8; ++ut) {
        bf8 wf[2];
        #pragma unroll
        for (int kt = 0; kt < 2; ++kt)
            wf[kt] = *(const bf8*)(ws + 0 + (((kt * 8 + ut) * 64 + lane) << 3));
        const f4 bias = *(const f4*)(b0 + ut * 16 + quad * 4);
        #pragma unroll
        for (int pt = 0; pt < 2; ++pt) {
            f4 acc = bias;
            #pragma unroll
            for (int kt = 0; kt < 2; ++kt)
                acc = __builtin_amdgcn_mfma_f32_16x16x32_bf16(wf[kt], af[pt][kt], acc, 0, 0, 0);
            store_tile(acc, pt, ut);
        }
    }
    __builtin_amdgcn_s_barrier();

    // ---- L1, L2: bufH(K=128) -> bufH ----
    #pragma unroll
    for (int layer = 0; layer < 2; ++layer) {
        const unsigned short* wsl = ws + (layer == 0 ? 8192 : 24576);
        const float* bias_p = (layer == 0) ? b1 : b2;
        #pragma unroll
        for (int pt = 0; pt < 2; ++pt)
            #pragma unroll
            for (int kt = 0; kt < 4; ++kt)
                af[pt][kt] = *(const bf8*)(bufH + pt * 16 * HSTRIDE + arow0 + kt * 32);
        #pragma unroll
        for (int ut = 0; ut < 8; ++ut) {
            bf8 wf[4];
            #pragma unroll
            for (int kt = 0; kt < 4; ++kt)
                wf[kt] = *(const bf8*)(wsl + (((kt * 8 + ut) * 64 + lane) << 3));
            const f4 bias = *(const f4*)(bias_p + ut * 16 + quad * 4);
            #pragma unroll
            for (int pt = 0; pt < 2; ++pt) {
                f4 acc = bias;
                #pragma unroll
                for (int kt = 0; kt < 4; ++kt)
                    acc = __builtin_amdgcn_mfma_f32_16x16x32_bf16(wf[kt], af[pt][kt], acc, 0, 0, 0);
                store_tile(acc, pt, ut);
            }
        }
        __builtin_amdgcn_s_barrier();
    }

    // ---- L3: concat(bufH 128, fbuf 63) K=192 -> bufH ----
    #pragma unroll
    for (int pt = 0; pt < 2; ++pt) {
        #pragma unroll
        for (int kt = 0; kt < 4; ++kt)
            af[pt][kt] = *(const bf8*)(bufH + pt * 16 * HSTRIDE + arow0 + kt * 32);
        #pragma unroll
        for (int kk = 0; kk < 2; ++kk)
            af[pt][4 + kk] = *(const bf8*)(fbuf + pt * 16 * FSTRIDE + frow0 + kk * 32);
    }
    #pragma unroll
    for (int ut = 0; ut < 8; ++ut) {
        bf8 wf[6];
        #pragma unroll
        for (int kt = 0; kt < 6; ++kt)
            wf[kt] = *(const bf8*)(ws + 40960 + (((kt * 8 + ut) * 64 + lane) << 3));
        const f4 bias = *(const f4*)(b3 + ut * 16 + quad * 4);
        #pragma unroll
        for (int pt = 0; pt < 2; ++pt) {
            f4 acc = bias;
            #pragma unroll
            for (int kt = 0; kt < 6; ++kt)
                acc = __builtin_amdgcn_mfma_f32_16x16x32_bf16(wf[kt], af[pt][kt], acc, 0, 0, 0);
            store_tile(acc, pt, ut);
        }
    }
    __builtin_amdgcn_s_barrier();

    // ---- output layer (K=128, N=3) + Rodrigues epilogue ----
    #pragma unroll
    for (int pt = 0; pt < 2; ++pt)
        #pragma unroll
        for (int kt = 0; kt < 4; ++kt)
            af[pt][kt] = *(const bf8*)(bufH + pt * 16 * HSTRIDE + arow0 + kt * 32);
    bf8 wf[4];
    #pragma unroll
    for (int kt = 0; kt < 4; ++kt)
        wf[kt] = *(const bf8*)(ws + 65536 + ((kt * 64 + lane) << 3));

    #pragma unroll
    for (int pt = 0; pt < 2; ++pt) {
        f4 acc;
        #pragma unroll
        for (int r = 0; r < 4; ++r) {
            const int u = quad * 4 + r;
            acc[r] = (u < 3) ? bo[u] : 0.0f;
        }
        #pragma unroll
        for (int kt = 0; kt < 4; ++kt)
            acc = __builtin_amdgcn_mfma_f32_16x16x32_bf16(wf[kt], af[pt][kt], acc, 0, 0, 0);

        const int pp = pt * 16 + lm;
        const float* cst = (const float*)(fbuf + pp * FSTRIDE + 64);
        const float g1 = cst[0], g2 = cst[1], g3 = cst[2];
        const float r0 = acc[0], r1 = acc[1], r2 = acc[2];
        const float theta = sqrtf(fmaf(r0, r0, fmaf(r1, r1, r2 * r2)) + 1e-12f);
        const float e0 = r0 / theta, e1 = r1 / theta, e2 = r2 / theta;
        const float a = sqrtf(fmaf(g1, g1, fmaf(g2, g2, g3 * g3)) + 1e-12f);
        const float v0 = g1 / a, v1 = g2 / a, v2 = g3 / a;
        const float ct = cosf(theta), st = sinf(theta);
        const float cx = e1 * v2 - e2 * v1;
        const float cy = e2 * v0 - e0 * v2;
        const float cz = e0 * v1 - e1 * v0;
        const float om = (1.0f - ct) * (e0 * v0 + e1 * v1 + e2 * v2);
        if (quad == 0) {
            const int pid2 = pbase + pp;
            out[4 * B + pid2 * 3 + 0] = a * (ct * v0 + st * cx + om * e0);
            out[4 * B + pid2 * 3 + 1] = a * (ct * v1 + st * cy + om * e1);
            out[4 * B + pid2 * 3 + 2] = a * (ct * v2 + st * cz + om * e2);
        }
    }
}

extern "C" void kernel_launch(void* const* d_in, const int* in_sizes, int n_in,
                              void* d_out, int out_size, void* d_ws, size_t ws_size,
                              hipStream_t stream)
{
    const float* x    = (const float*)d_in[0];
    const float* grid = (const float*)d_in[1];
    const float* w0   = (const float*)d_in[2];
    const float* b0   = (const float*)d_in[3];
    const float* w1   = (const float*)d_in[4];
    const float* b1   = (const float*)d_in[5];
    const float* w2   = (const float*)d_in[6];
    const float* b2   = (const float*)d_in[7];
    const float* w3   = (const float*)d_in[8];
    const float* b3   = (const float*)d_in[9];
    const float* wo   = (const float*)d_in[10];
    const float* bo   = (const float*)d_in[11];
    float* out = (float*)d_out;
    unsigned short* ws = (unsigned short*)d_ws;
    unsigned short* dg = ws + DG_OFF_SH;

    const int B = in_sizes[0] / 3;        // 1,048,576
    swizzle_w<<<(WS_TOTAL + 255) / 256, 256, 0, stream>>>(w0, w1, w2, w3, wo, ws);
    if (ws_size >= WS_NEED) {
        make_dgrid<<<16384, 256, 0, stream>>>(grid, dg);
        voxmlp<true><<<B / 128, 256, 0, stream>>>(x, grid, ws, dg, b0, b1, b2, b3, bo, out, B);
    } else {
        voxmlp<false><<<B / 128, 256, 0, stream>>>(x, grid, ws, dg, b0, b1, b2, b3, bo, out, B);
    }
}

// Round 5
// 372.199 us; speedup vs baseline: 7.3859x; 1.0401x over previous
//
#include <hip/hip_runtime.h>

// ---------------------------------------------------------------------------
// VoxMLP round 5: VALU-diet version of R4.
//   prep (1 launch): [blocks 0..263] swizzle weights -> bf16 MFMA fragments
//     (with feature-K permutation), [blocks 264..16647] build bf16x4
//     [v,gx,gy,gz] data grid (134 MB, L3-resident).
//   voxmlp: 4 independent waves x 32 points. Lanes 0..31: 8x8B dgrid gather
//     +trilinear (out0/out1 + LDS stash). Lanes 32..63: pos-enc features,
//     packed via v_cvt_pk_bf16_f32 into 32 dwords -> 8 ds_write_b128
//     (bank-uniform; was 63 scalar b16 = 4-way conflicts).
//   MLP: v_mfma_f32_16x16x32_bf16, A=weights, B=activations[k][point],
//     C=[unit][point]; store_tile uses v_cvt_pk_bf16_f32 (2 ops vs ~14).
//   Feature K-permutation (applied identically in prep and voxmlp):
//     k'=0,1,2 -> x,y,z ; k'=3 -> 0 ; k'=4+6b+2d+c -> (c? cos:sin)(2^b*crd_d)
// ---------------------------------------------------------------------------

typedef __attribute__((ext_vector_type(8))) short bf8;   // 8 bf16 = 4 VGPR
typedef __attribute__((ext_vector_type(4))) float f4;

__device__ __forceinline__ float bf2f(unsigned int u) {
    union { float f; unsigned int i; } v; v.i = u << 16; return v.f;
}
__device__ __forceinline__ unsigned short f2bf(float f) {
    union { float f; unsigned int i; } v; v.f = f;
    unsigned int x = v.i;
    return (unsigned short)((x + 0x7fffu + ((x >> 16) & 1u)) >> 16);
}
// packed f32x2 -> bf16x2 (RNE). low16 = a, high16 = b.
__device__ __forceinline__ unsigned int pkbf(float a, float b) {
    unsigned int r;
    asm("v_cvt_pk_bf16_f32 %0, %1, %2" : "=v"(r) : "v"(a), "v"(b));
    return r;
}
__device__ __forceinline__ float gv(const float* __restrict__ g, int i, int j, int k) {
    return g[(i * 256 + j) * 256 + k];
}
// feature permutation: slot k' -> original feature index (or -1 = zero pad)
__device__ __forceinline__ int featmap(int kp) {
    if (kp < 3) return kp;
    if (kp == 3) return -1;
    const int m = kp - 4, b = m / 6, r = m - 6 * b, d = r >> 1, c = r & 1;
    return 3 + 6 * b + 3 * c + d;
}

// ---- d_ws layout ----
// shorts [0, 67584): swizzled weights (L0,L1,L2,L3,out)
// bytes  [262144, +16.7M*8): bf16x4 data grid
#define WS_TOTAL 67584
#define SWZ_BLOCKS 264          // 264*256 == 67584
#define DG_OFF_SH 131072
#define WS_NEED (262144ull + 16777216ull * 8ull)

__global__ __launch_bounds__(256) void prep(
    const float* __restrict__ g,
    const float* __restrict__ w0, const float* __restrict__ w1,
    const float* __restrict__ w2, const float* __restrict__ w3,
    const float* __restrict__ wo,
    unsigned short* __restrict__ ws, unsigned short* __restrict__ dg,
    int do_dgrid)
{
    const int bid = blockIdx.x;
    if (bid < SWZ_BLOCKS) {
        // ---------------- weight swizzle ----------------
        int idx = bid * 256 + threadIdx.x;
        const float* src; int base, NT, Kact, Nact, ld;
        if (idx < 8192)       { src = w0; base = 0;     NT = 8; Kact = 64;  Nact = 128; ld = 128; }
        else if (idx < 24576) { src = w1; base = 8192;  NT = 8; Kact = 128; Nact = 128; ld = 128; }
        else if (idx < 40960) { src = w2; base = 24576; NT = 8; Kact = 128; Nact = 128; ld = 128; }
        else if (idx < 65536) { src = w3; base = 40960; NT = 8; Kact = 192; Nact = 128; ld = 128; }
        else                  { src = wo; base = 65536; NT = 1; Kact = 128; Nact = 3;   ld = 3;   }
        int local = idx - base;
        int j = local & 7;
        int lane = (local >> 3) & 63;
        int chunk = local >> 9;              // = kt*NT + nt
        int nt = chunk % NT, kt = chunk / NT;
        int k = kt * 32 + ((lane >> 4) << 3) + j;   // fragment row (K)
        int n = nt * 16 + (lane & 15);              // fragment col (unit)
        float v = 0.0f;
        if (k < Kact && n < Nact) {
            int ko = k;
            if (base == 0)            ko = featmap(k);                 // L0: permuted
            else if (base == 40960 && k >= 128) {                      // L3 feats part
                int f = featmap(k - 128);
                ko = (f < 0) ? -1 : 128 + f;
            }
            if (ko >= 0) v = src[ko * ld + n];
        }
        ws[idx] = f2bf(v);
    } else if (do_dgrid) {
        // ---------------- data grid build ----------------
        const int t  = (bid - SWZ_BLOCKS) * 256 + threadIdx.x;   // [0, 2^22)
        const int k0 = (t & 63) << 2;
        const int j  = (t >> 6) & 255;
        const int i  = t >> 14;
        const float* row = g + (i * 256 + j) * 256;
        const f4 self = *(const f4*)(row + k0);
        const f4 xp = *(const f4*)(g + (min(i + 1, 255) * 256 + j) * 256 + k0);
        const f4 xm = *(const f4*)(g + (max(i - 1, 0)   * 256 + j) * 256 + k0);
        const f4 yp = *(const f4*)(g + (i * 256 + min(j + 1, 255)) * 256 + k0);
        const f4 ym = *(const f4*)(g + (i * 256 + max(j - 1, 0))   * 256 + k0);
        const float zlo = row[max(k0 - 1, 0)];
        const float zhi = row[min(k0 + 4, 255)];
        float zv[6] = {zlo, self[0], self[1], self[2], self[3], zhi};
        unsigned int o[8];
        #pragma unroll
        for (int q = 0; q < 4; ++q) {
            o[q * 2 + 0] = pkbf(self[q], (xp[q] - xm[q]) * 63.75f);
            o[q * 2 + 1] = pkbf((yp[q] - ym[q]) * 63.75f, (zv[q + 2] - zv[q]) * 63.75f);
        }
        unsigned short* dst = dg + (size_t)(((i * 256 + j) * 256 + k0)) * 4;
        *(uint4*)(dst)     = *(const uint4*)(o);
        *(uint4*)(dst + 8) = *(const uint4*)(o + 4);
    }
}

// per-wave LDS: bufH 32x136 bf16 (8704 B), fbuf 32x72 bf16 (4608 B)
// fbuf row: shorts [0..63] features; [64..69] 3 fp32 c1..c3 stash.
#define WV_SH 6656
#define HSTRIDE 136
#define FSTRIDE 72

template<bool FAST>
__global__ __launch_bounds__(256, 3) void voxmlp(
    const float* __restrict__ x, const float* __restrict__ grid,
    const unsigned short* __restrict__ ws, const unsigned short* __restrict__ dg,
    const float* __restrict__ b0, const float* __restrict__ b1,
    const float* __restrict__ b2, const float* __restrict__ b3,
    const float* __restrict__ bo,
    float* __restrict__ out, int B)
{
    __shared__ unsigned short smem[WV_SH * 4];   // 53248 B -> 3 blocks/CU

    const int lane = threadIdx.x & 63;
    const int wave = threadIdx.x >> 6;
    const int quad = lane >> 4;
    const int lm   = lane & 15;
    unsigned short* bufH = smem + wave * WV_SH;
    unsigned short* fbuf = bufH + 32 * HSTRIDE;

    const int pbase = blockIdx.x * 128 + wave * 32;

    // ================= Phase 1 ============================================
    const int p2   = lane & 31;
    const int role = lane >> 5;
    const int pid  = pbase + p2;

    const float px = x[pid * 3 + 0];
    const float py = x[pid * 3 + 1];
    const float pz = x[pid * 3 + 2];

    if (role == 0) {
        const float fx = (px + 1.0f) * 127.5f;
        const float fy = (py + 1.0f) * 127.5f;
        const float fz = (pz + 1.0f) * 127.5f;
        const float fx0 = floorf(fx), fy0 = floorf(fy), fz0 = floorf(fz);
        const float xd = fx - fx0, yd = fy - fy0, zd = fz - fz0;
        const int ix0 = min(max((int)fx0, 0), 255);
        const int iy0 = min(max((int)fy0, 0), 255);
        const int iz0 = min(max((int)fz0, 0), 255);
        const int ix1 = min(ix0 + 1, 255);
        const int iy1 = min(iy0 + 1, 255);
        const int iz1 = min(iz0 + 1, 255);

        float ret0 = 0.f, c1 = 0.f, c2 = 0.f, c3 = 0.f;
        if (FAST) {
            #pragma unroll
            for (int c = 0; c < 8; ++c) {
                const int i = (c & 4) ? ix1 : ix0;
                const int j = (c & 2) ? iy1 : iy0;
                const int k = (c & 1) ? iz1 : iz0;
                const float wgt = ((c & 4) ? xd : 1.0f - xd) *
                                  ((c & 2) ? yd : 1.0f - yd) *
                                  ((c & 1) ? zd : 1.0f - zd);
                const uint2 w = *(const uint2*)(dg + (size_t)((i * 256 + j) * 256 + k) * 4);
                ret0 = fmaf(wgt, bf2f(w.x & 0xffffu), ret0);
                c1   = fmaf(wgt, bf2f(w.x >> 16),     c1);
                c2   = fmaf(wgt, bf2f(w.y & 0xffffu), c2);
                c3   = fmaf(wgt, bf2f(w.y >> 16),     c3);
            }
        } else {
            #pragma unroll
            for (int c = 0; c < 8; ++c) {
                const int i = (c & 4) ? ix1 : ix0;
                const int j = (c & 2) ? iy1 : iy0;
                const int k = (c & 1) ? iz1 : iz0;
                const float wgt = ((c & 4) ? xd : 1.0f - xd) *
                                  ((c & 2) ? yd : 1.0f - yd) *
                                  ((c & 1) ? zd : 1.0f - zd);
                const float v  = gv(grid, i, j, k);
                const float gx = (gv(grid, min(i + 1, 255), j, k) - gv(grid, max(i - 1, 0), j, k)) * 63.75f;
                const float gy = (gv(grid, i, min(j + 1, 255), k) - gv(grid, i, max(j - 1, 0), k)) * 63.75f;
                const float gz = (gv(grid, i, j, min(k + 1, 255)) - gv(grid, i, j, max(k - 1, 0))) * 63.75f;
                ret0 = fmaf(wgt, v,  ret0);
                c1   = fmaf(wgt, gx, c1);
                c2   = fmaf(wgt, gy, c2);
                c3   = fmaf(wgt, gz, c3);
            }
        }
        out[pid] = ret0;
        out[B + pid * 3 + 0] = c1;
        out[B + pid * 3 + 1] = c2;
        out[B + pid * 3 + 2] = c3;
        float* cst = (float*)(fbuf + p2 * FSTRIDE + 64);
        cst[0] = c1; cst[1] = c2; cst[2] = c3;
    } else {
        // features, packed: dw0=(x,y) dw1=(z,0) dw[2+3b+d]=(sin,cos)
        unsigned int f[32];
        f[0] = pkbf(px, py);
        f[1] = pkbf(pz, 0.0f);
        const float crd[3] = {px, py, pz};
        float s = 1.0f;
        #pragma unroll
        for (int b = 0; b < 10; ++b) {
            #pragma unroll
            for (int d = 0; d < 3; ++d) {
                float sv, cv;
                __sincosf(crd[d] * s, &sv, &cv);
                f[2 + b * 3 + d] = pkbf(sv, cv);
            }
            s *= 2.0f;
        }
        unsigned short* fb = fbuf + p2 * FSTRIDE;   // 144B-aligned -> b128 ok
        #pragma unroll
        for (int i = 0; i < 8; ++i)
            *(uint4*)(fb + i * 8) = *(const uint4*)(&f[i * 4]);
    }
    __builtin_amdgcn_s_barrier();   // phase-align waves (L1 weight reuse)

    // ================= MLP via MFMA ========================================
    bf8 af[2][6];
    const int arow0 = lm * HSTRIDE + quad * 8;
    const int frow0 = lm * FSTRIDE + quad * 8;

    auto store_tile = [&](f4 acc, int pt, int ut) {
        uint2 pk;
        pk.x = pkbf(fmaxf(acc[0], 0.f), fmaxf(acc[1], 0.f));
        pk.y = pkbf(fmaxf(acc[2], 0.f), fmaxf(acc[3], 0.f));
        *(uint2*)(bufH + (pt * 16 + lm) * HSTRIDE + ut * 16 + quad * 4) = pk;
    };

    // ---- L0: fbuf(K=64) -> bufH ----
    #pragma unroll
    for (int pt = 0; pt < 2; ++pt)
        #pragma unroll
        for (int kt = 0; kt < 2; ++kt)
            af[pt][kt] = *(const bf8*)(fbuf + pt * 16 * FSTRIDE + frow0 + kt * 32);
    #pragma unroll
    for (int ut = 0; ut < 8; ++ut) {
        bf8 wf[2];
        #pragma unroll
        for (int kt = 0; kt < 2; ++kt)
            wf[kt] = *(const bf8*)(ws + 0 + (((kt * 8 + ut) * 64 + lane) << 3));
        const f4 bias = *(const f4*)(b0 + ut * 16 + quad * 4);
        #pragma unroll
        for (int pt = 0; pt < 2; ++pt) {
            f4 acc = bias;
            #pragma unroll
            for (int kt = 0; kt < 2; ++kt)
                acc = __builtin_amdgcn_mfma_f32_16x16x32_bf16(wf[kt], af[pt][kt], acc, 0, 0, 0);
            store_tile(acc, pt, ut);
        }
    }
    __builtin_amdgcn_s_barrier();

    // ---- L1, L2: bufH(K=128) -> bufH ----
    #pragma unroll
    for (int layer = 0; layer < 2; ++layer) {
        const unsigned short* wsl = ws + (layer == 0 ? 8192 : 24576);
        const float* bias_p = (layer == 0) ? b1 : b2;
        #pragma unroll
        for (int pt = 0; pt < 2; ++pt)
            #pragma unroll
            for (int kt = 0; kt < 4; ++kt)
                af[pt][kt] = *(const bf8*)(bufH + pt * 16 * HSTRIDE + arow0 + kt * 32);
        #pragma unroll
        for (int ut = 0; ut < 8; ++ut) {
            bf8 wf[4];
            #pragma unroll
            for (int kt = 0; kt < 4; ++kt)
                wf[kt] = *(const bf8*)(wsl + (((kt * 8 + ut) * 64 + lane) << 3));
            const f4 bias = *(const f4*)(bias_p + ut * 16 + quad * 4);
            #pragma unroll
            for (int pt = 0; pt < 2; ++pt) {
                f4 acc = bias;
                #pragma unroll
                for (int kt = 0; kt < 4; ++kt)
                    acc = __builtin_amdgcn_mfma_f32_16x16x32_bf16(wf[kt], af[pt][kt], acc, 0, 0, 0);
                store_tile(acc, pt, ut);
            }
        }
        __builtin_amdgcn_s_barrier();
    }

    // ---- L3: concat(bufH 128, fbuf 64) K=192 -> bufH ----
    #pragma unroll
    for (int pt = 0; pt < 2; ++pt) {
        #pragma unroll
        for (int kt = 0; kt < 4; ++kt)
            af[pt][kt] = *(const bf8*)(bufH + pt * 16 * HSTRIDE + arow0 + kt * 32);
        #pragma unroll
        for (int kk = 0; kk < 2; ++kk)
            af[pt][4 + kk] = *(const bf8*)(fbuf + pt * 16 * FSTRIDE + frow0 + kk * 32);
    }
    #pragma unroll
    for (int ut = 0; ut < 8; ++ut) {
        bf8 wf[6];
        #pragma unroll
        for (int kt = 0; kt < 6; ++kt)
            wf[kt] = *(const bf8*)(ws + 40960 + (((kt * 8 + ut) * 64 + lane) << 3));
        const f4 bias = *(const f4*)(b3 + ut * 16 + quad * 4);
        #pragma unroll
        for (int pt = 0; pt < 2; ++pt) {
            f4 acc = bias;
            #pragma unroll
            for (int kt = 0; kt < 6; ++kt)
                acc = __builtin_amdgcn_mfma_f32_16x16x32_bf16(wf[kt], af[pt][kt], acc, 0, 0, 0);
            store_tile(acc, pt, ut);
        }
    }
    __builtin_amdgcn_s_barrier();

    // ---- output layer (K=128, N=3) + Rodrigues epilogue ----
    #pragma unroll
    for (int pt = 0; pt < 2; ++pt)
        #pragma unroll
        for (int kt = 0; kt < 4; ++kt)
            af[pt][kt] = *(const bf8*)(bufH + pt * 16 * HSTRIDE + arow0 + kt * 32);
    bf8 wf[4];
    #pragma unroll
    for (int kt = 0; kt < 4; ++kt)
        wf[kt] = *(const bf8*)(ws + 65536 + ((kt * 64 + lane) << 3));

    #pragma unroll
    for (int pt = 0; pt < 2; ++pt) {
        f4 acc;
        #pragma unroll
        for (int r = 0; r < 4; ++r) {
            const int u = quad * 4 + r;
            acc[r] = (u < 3) ? bo[u] : 0.0f;
        }
        #pragma unroll
        for (int kt = 0; kt < 4; ++kt)
            acc = __builtin_amdgcn_mfma_f32_16x16x32_bf16(wf[kt], af[pt][kt], acc, 0, 0, 0);

        const int pp = pt * 16 + lm;
        const float* cst = (const float*)(fbuf + pp * FSTRIDE + 64);
        const float g1 = cst[0], g2 = cst[1], g3 = cst[2];
        const float r0 = acc[0], r1 = acc[1], r2 = acc[2];
        const float theta = sqrtf(fmaf(r0, r0, fmaf(r1, r1, r2 * r2)) + 1e-12f);
        const float it = __builtin_amdgcn_rcpf(theta);
        const float e0 = r0 * it, e1 = r1 * it, e2 = r2 * it;
        const float a = sqrtf(fmaf(g1, g1, fmaf(g2, g2, g3 * g3)) + 1e-12f);
        const float ia = __builtin_amdgcn_rcpf(a);
        const float v0 = g1 * ia, v1 = g2 * ia, v2 = g3 * ia;
        float st, ct;
        __sincosf(theta, &st, &ct);
        const float cx = e1 * v2 - e2 * v1;
        const float cy = e2 * v0 - e0 * v2;
        const float cz = e0 * v1 - e1 * v0;
        const float om = (1.0f - ct) * (e0 * v0 + e1 * v1 + e2 * v2);
        if (quad == 0) {
            const int pid2 = pbase + pp;
            out[4 * B + pid2 * 3 + 0] = a * (ct * v0 + st * cx + om * e0);
            out[4 * B + pid2 * 3 + 1] = a * (ct * v1 + st * cy + om * e1);
            out[4 * B + pid2 * 3 + 2] = a * (ct * v2 + st * cz + om * e2);
        }
    }
}

extern "C" void kernel_launch(void* const* d_in, const int* in_sizes, int n_in,
                              void* d_out, int out_size, void* d_ws, size_t ws_size,
                              hipStream_t stream)
{
    const float* x    = (const float*)d_in[0];
    const float* grid = (const float*)d_in[1];
    const float* w0   = (const float*)d_in[2];
    const float* b0   = (const float*)d_in[3];
    const float* w1   = (const float*)d_in[4];
    const float* b1   = (const float*)d_in[5];
    const float* w2   = (const float*)d_in[6];
    const float* b2   = (const float*)d_in[7];
    const float* w3   = (const float*)d_in[8];
    const float* b3   = (const float*)d_in[9];
    const float* wo   = (const float*)d_in[10];
    const float* bo   = (const float*)d_in[11];
    float* out = (float*)d_out;
    unsigned short* ws = (unsigned short*)d_ws;
    unsigned short* dg = ws + DG_OFF_SH;

    const int B = in_sizes[0] / 3;        // 1,048,576
    const int fast = (ws_size >= WS_NEED) ? 1 : 0;
    const int nprep = fast ? (SWZ_BLOCKS + 16384) : SWZ_BLOCKS;
    prep<<<nprep, 256, 0, stream>>>(grid, w0, w1, w2, w3, wo, ws, dg, fast);
    if (fast)
        voxmlp<true><<<B / 128, 256, 0, stream>>>(x, grid, ws, dg, b0, b1, b2, b3, bo, out, B);
    else
        voxmlp<false><<<B / 128, 256, 0, stream>>>(x, grid, ws, dg, b0, b1, b2, b3, bo, out, B);
}

// Round 6
// 368.082 us; speedup vs baseline: 7.4685x; 1.0112x over previous
//
#include <hip/hip_runtime.h>

// ---------------------------------------------------------------------------
// VoxMLP round 6: fp8(e4m3) MFMA MLP + bf16 dgrid gather.
//   prep: [blocks 0..263] weights -> fp8 MFMA fragments (wo pre-scaled 2^13,
//         feature-K permutation); [blocks 264..8455] bf16x4 [v,gx,gy,gz]
//         data grid (134 MB, L3-resident), 8 voxels/thread.
//   voxmlp: 4 independent waves x 32 points. Lanes 0..31: 8x8B dgrid gather
//     +trilinear (out0/out1 + LDS stash). Lanes 32..63: pos-enc features ->
//     fp8 -> LDS. MLP via v_mfma_f32_16x16x32_fp8_fp8 (A=weights[unit],
//     B=activations[k][point], C=[unit][point]); epilogue scales by 2^-13.
//   LDS geometry (conflict-audited): bufH row 136 B (34 dw ≡ 2 mod 32 ->
//     2-way, free), fbuf row 88 B (22 dw -> 16 start banks, 2-way).
//   LDS/block 28672 B -> 5 blocks/CU; __launch_bounds__(256,5).
// ---------------------------------------------------------------------------

typedef __attribute__((ext_vector_type(4))) float f4;
typedef long long llg;   // 8 x fp8 = 2 VGPRs

__device__ __forceinline__ float bf2f(unsigned int u) {
    union { float f; unsigned int i; } v; v.i = u << 16; return v.f;
}
__device__ __forceinline__ unsigned short f2bf(float f) {
    union { float f; unsigned int i; } v; v.f = f;
    unsigned int x = v.i;
    return (unsigned short)((x + 0x7fffu + ((x >> 16) & 1u)) >> 16);
}
__device__ __forceinline__ unsigned int pkbf(float a, float b) {
    unsigned int r;
    asm("v_cvt_pk_bf16_f32 %0, %1, %2" : "=v"(r) : "v"(a), "v"(b));
    return r;
}
__device__ __forceinline__ float gv(const float* __restrict__ g, int i, int j, int k) {
    return g[(i * 256 + j) * 256 + k];
}
// feature permutation: slot k' -> original feature index (or -1 = zero pad)
__device__ __forceinline__ int featmap(int kp) {
    if (kp < 3) return kp;
    if (kp == 3) return -1;
    const int m = kp - 4, b = m / 6, r = m - 6 * b, d = r >> 1, c = r & 1;
    return 3 + 6 * b + 3 * c + d;
}

// ---- d_ws layout ----
// bytes [0, 67584): fp8 weight fragments: L0@0(K64), L1@8192(K128),
//   L2@24576, L3@40960(K192), out@65536(K128,NT1, wo*2^13)
// shorts from 131072 (byte 262144): bf16x4 data grid (16.7M voxels * 8 B)
#define WS_TOTAL 67584
#define SWZ_BLOCKS 264          // 264*256 == 67584 (one byte per thread)
#define DG_BLOCKS 8192          // 2^21 threads x 8 voxels
#define DG_OFF_SH 131072
#define WS_NEED (262144ull + 16777216ull * 8ull)
#define WO_SCALE 8192.0f
#define WO_INV   (1.0f / 8192.0f)

__global__ __launch_bounds__(256) void prep(
    const float* __restrict__ g,
    const float* __restrict__ w0, const float* __restrict__ w1,
    const float* __restrict__ w2, const float* __restrict__ w3,
    const float* __restrict__ wo,
    unsigned char* __restrict__ ws8, unsigned short* __restrict__ dg,
    int do_dgrid)
{
    const int bid = blockIdx.x;
    if (bid < SWZ_BLOCKS) {
        // ---------------- weight swizzle -> fp8 ----------------
        int idx = bid * 256 + threadIdx.x;
        const float* src; int base, NT, Kact, Nact, ld;
        if (idx < 8192)       { src = w0; base = 0;     NT = 8; Kact = 64;  Nact = 128; ld = 128; }
        else if (idx < 24576) { src = w1; base = 8192;  NT = 8; Kact = 128; Nact = 128; ld = 128; }
        else if (idx < 40960) { src = w2; base = 24576; NT = 8; Kact = 128; Nact = 128; ld = 128; }
        else if (idx < 65536) { src = w3; base = 40960; NT = 8; Kact = 192; Nact = 128; ld = 128; }
        else                  { src = wo; base = 65536; NT = 1; Kact = 128; Nact = 3;   ld = 3;   }
        int local = idx - base;
        int j = local & 7;
        int lane = (local >> 3) & 63;
        int chunk = local >> 9;              // = kt*NT + nt
        int nt = chunk % NT, kt = chunk / NT;
        int k = kt * 32 + ((lane >> 4) << 3) + j;   // k = kt*32 + quad*8 + j
        int n = nt * 16 + (lane & 15);              // unit = nt*16 + (lane&15)
        float v = 0.0f;
        if (k < Kact && n < Nact) {
            int ko = k;
            if (base == 0)            ko = featmap(k);
            else if (base == 40960 && k >= 128) {
                int f = featmap(k - 128);
                ko = (f < 0) ? -1 : 128 + f;
            }
            if (ko >= 0) v = src[ko * ld + n];
            if (base == 65536) v *= WO_SCALE;        // keep wo out of fp8 underflow
        }
        int p = __builtin_amdgcn_cvt_pk_fp8_f32(v, v, 0, false);
        ws8[idx] = (unsigned char)(p & 0xff);
    } else if (do_dgrid) {
        // ---------------- data grid build (8 voxels/thread) ----------------
        const int t  = (bid - SWZ_BLOCKS) * 256 + threadIdx.x;   // [0, 2^21)
        const int k0 = (t & 31) << 3;
        const int j  = (t >> 5) & 255;
        const int i  = t >> 13;
        const float* row = g + (i * 256 + j) * 256;
        const float* rxp = g + (min(i + 1, 255) * 256 + j) * 256;
        const float* rxm = g + (max(i - 1, 0)   * 256 + j) * 256;
        const float* ryp = g + (i * 256 + min(j + 1, 255)) * 256;
        const float* rym = g + (i * 256 + max(j - 1, 0))   * 256;
        float se[8], sxp[8], sxm[8], syp[8], sym[8];
        {
            f4 a = *(const f4*)(row + k0), b = *(const f4*)(row + k0 + 4);
            #pragma unroll
            for (int q = 0; q < 4; ++q) { se[q] = a[q]; se[q + 4] = b[q]; }
            a = *(const f4*)(rxp + k0); b = *(const f4*)(rxp + k0 + 4);
            #pragma unroll
            for (int q = 0; q < 4; ++q) { sxp[q] = a[q]; sxp[q + 4] = b[q]; }
            a = *(const f4*)(rxm + k0); b = *(const f4*)(rxm + k0 + 4);
            #pragma unroll
            for (int q = 0; q < 4; ++q) { sxm[q] = a[q]; sxm[q + 4] = b[q]; }
            a = *(const f4*)(ryp + k0); b = *(const f4*)(ryp + k0 + 4);
            #pragma unroll
            for (int q = 0; q < 4; ++q) { syp[q] = a[q]; syp[q + 4] = b[q]; }
            a = *(const f4*)(rym + k0); b = *(const f4*)(rym + k0 + 4);
            #pragma unroll
            for (int q = 0; q < 4; ++q) { sym[q] = a[q]; sym[q + 4] = b[q]; }
        }
        float zv[10];
        zv[0] = row[max(k0 - 1, 0)];
        #pragma unroll
        for (int q = 0; q < 8; ++q) zv[q + 1] = se[q];
        zv[9] = row[min(k0 + 8, 255)];
        unsigned int o[16];
        #pragma unroll
        for (int q = 0; q < 8; ++q) {
            o[q * 2 + 0] = pkbf(se[q], (sxp[q] - sxm[q]) * 63.75f);
            o[q * 2 + 1] = pkbf((syp[q] - sym[q]) * 63.75f, (zv[q + 2] - zv[q]) * 63.75f);
        }
        unsigned short* dst = dg + (size_t)(((i * 256 + j) * 256 + k0)) * 4;
        #pragma unroll
        for (int q = 0; q < 4; ++q)
            *(uint4*)(dst + q * 8) = *(const uint4*)(&o[q * 4]);
    }
}

// per-wave LDS (bytes): bufH 32 rows x 136 B (units 0..127 + pad),
// fbuf 32 rows x 88 B: [0..63] fp8 features, [64..75] 3 fp32 c1..c3 stash.
#define HSTRIDE_B 136
#define FSTRIDE_B 88
#define WV_BYTES (32 * HSTRIDE_B + 32 * FSTRIDE_B)   // 7168

template<bool FAST>
__global__ __launch_bounds__(256, 5) void voxmlp(
    const float* __restrict__ x, const float* __restrict__ grid,
    const unsigned char* __restrict__ ws8, const unsigned short* __restrict__ dg,
    const float* __restrict__ b0, const float* __restrict__ b1,
    const float* __restrict__ b2, const float* __restrict__ b3,
    const float* __restrict__ bo,
    float* __restrict__ out, int B)
{
    __shared__ unsigned char smem[WV_BYTES * 4];   // 28672 B -> 5 blocks/CU

    const int lane = threadIdx.x & 63;
    const int wave = threadIdx.x >> 6;
    const int quad = lane >> 4;
    const int lm   = lane & 15;
    unsigned char* bufH = smem + wave * WV_BYTES;
    unsigned char* fbuf = bufH + 32 * HSTRIDE_B;

    const int pbase = blockIdx.x * 128 + wave * 32;

    // ================= Phase 1 ============================================
    const int p2   = lane & 31;
    const int role = lane >> 5;
    const int pid  = pbase + p2;

    const float px = x[pid * 3 + 0];
    const float py = x[pid * 3 + 1];
    const float pz = x[pid * 3 + 2];

    if (role == 0) {
        const float fx = (px + 1.0f) * 127.5f;
        const float fy = (py + 1.0f) * 127.5f;
        const float fz = (pz + 1.0f) * 127.5f;
        const float fx0 = floorf(fx), fy0 = floorf(fy), fz0 = floorf(fz);
        const float xd = fx - fx0, yd = fy - fy0, zd = fz - fz0;
        const int ix0 = min(max((int)fx0, 0), 255);
        const int iy0 = min(max((int)fy0, 0), 255);
        const int iz0 = min(max((int)fz0, 0), 255);
        const int ix1 = min(ix0 + 1, 255);
        const int iy1 = min(iy0 + 1, 255);
        const int iz1 = min(iz0 + 1, 255);

        float ret0 = 0.f, c1 = 0.f, c2 = 0.f, c3 = 0.f;
        if (FAST) {
            #pragma unroll
            for (int c = 0; c < 8; ++c) {
                const int i = (c & 4) ? ix1 : ix0;
                const int j = (c & 2) ? iy1 : iy0;
                const int k = (c & 1) ? iz1 : iz0;
                const float wgt = ((c & 4) ? xd : 1.0f - xd) *
                                  ((c & 2) ? yd : 1.0f - yd) *
                                  ((c & 1) ? zd : 1.0f - zd);
                const uint2 w = *(const uint2*)(dg + (size_t)((i * 256 + j) * 256 + k) * 4);
                ret0 = fmaf(wgt, bf2f(w.x & 0xffffu), ret0);
                c1   = fmaf(wgt, bf2f(w.x >> 16),     c1);
                c2   = fmaf(wgt, bf2f(w.y & 0xffffu), c2);
                c3   = fmaf(wgt, bf2f(w.y >> 16),     c3);
            }
        } else {
            #pragma unroll
            for (int c = 0; c < 8; ++c) {
                const int i = (c & 4) ? ix1 : ix0;
                const int j = (c & 2) ? iy1 : iy0;
                const int k = (c & 1) ? iz1 : iz0;
                const float wgt = ((c & 4) ? xd : 1.0f - xd) *
                                  ((c & 2) ? yd : 1.0f - yd) *
                                  ((c & 1) ? zd : 1.0f - zd);
                const float v  = gv(grid, i, j, k);
                const float gx = (gv(grid, min(i + 1, 255), j, k) - gv(grid, max(i - 1, 0), j, k)) * 63.75f;
                const float gy = (gv(grid, i, min(j + 1, 255), k) - gv(grid, i, max(j - 1, 0), k)) * 63.75f;
                const float gz = (gv(grid, i, j, min(k + 1, 255)) - gv(grid, i, j, max(k - 1, 0))) * 63.75f;
                ret0 = fmaf(wgt, v,  ret0);
                c1   = fmaf(wgt, gx, c1);
                c2   = fmaf(wgt, gy, c2);
                c3   = fmaf(wgt, gz, c3);
            }
        }
        out[pid] = ret0;
        out[B + pid * 3 + 0] = c1;
        out[B + pid * 3 + 1] = c2;
        out[B + pid * 3 + 2] = c3;
        float* cst = (float*)(fbuf + p2 * FSTRIDE_B + 64);
        cst[0] = c1; cst[1] = c2; cst[2] = c3;
    } else {
        // 63 features in permuted slot order, fp8-packed, 4x ds_write_b64
        float s[64];
        s[0] = px; s[1] = py; s[2] = pz; s[3] = 0.0f;
        const float crd[3] = {px, py, pz};
        float sc = 1.0f;
        #pragma unroll
        for (int b = 0; b < 10; ++b) {
            #pragma unroll
            for (int d = 0; d < 3; ++d) {
                float sv, cv;
                __sincosf(crd[d] * sc, &sv, &cv);
                s[4 + b * 6 + d * 2 + 0] = sv;
                s[4 + b * 6 + d * 2 + 1] = cv;
            }
            sc *= 2.0f;
        }
        unsigned int dw[16];
        #pragma unroll
        for (int i = 0; i < 16; ++i) {
            int d = __builtin_amdgcn_cvt_pk_fp8_f32(s[4 * i + 0], s[4 * i + 1], 0, false);
            d     = __builtin_amdgcn_cvt_pk_fp8_f32(s[4 * i + 2], s[4 * i + 3], d, true);
            dw[i] = (unsigned int)d;
        }
        unsigned char* fb = fbuf + p2 * FSTRIDE_B;
        #pragma unroll
        for (int i = 0; i < 4; ++i) {
            uint2 pk; pk.x = dw[2 * i]; pk.y = dw[2 * i + 1];
            *(uint2*)(fb + i * 8) = pk;
        }
        // second half of the 16 dwords: bytes 32..63
        #pragma unroll
        for (int i = 4; i < 8; ++i) {
            uint2 pk; pk.x = dw[2 * i]; pk.y = dw[2 * i + 1];
            *(uint2*)(fb + i * 8) = pk;
        }
    }
    __builtin_amdgcn_s_barrier();   // phase-align waves (L1 weight reuse)

    // ================= MLP via fp8 MFMA ====================================
    llg af[2][6];
    const int arow0 = lm * HSTRIDE_B + quad * 8;
    const int frow0 = lm * FSTRIDE_B + quad * 8;

    auto store_tile = [&](f4 acc, int pt, int ut) {
        int d = __builtin_amdgcn_cvt_pk_fp8_f32(fmaxf(acc[0], 0.f), fmaxf(acc[1], 0.f), 0, false);
        d     = __builtin_amdgcn_cvt_pk_fp8_f32(fmaxf(acc[2], 0.f), fmaxf(acc[3], 0.f), d, true);
        *(int*)(bufH + (pt * 16 + lm) * HSTRIDE_B + ut * 16 + quad * 4) = d;
    };

    // ---- L0: fbuf(K=64) -> bufH ----
    #pragma unroll
    for (int pt = 0; pt < 2; ++pt)
        #pragma unroll
        for (int kt = 0; kt < 2; ++kt)
            af[pt][kt] = *(const llg*)(fbuf + pt * 16 * FSTRIDE_B + frow0 + kt * 32);
    #pragma unroll
    for (int ut = 0; ut < 8; ++ut) {
        llg wf[2];
        #pragma unroll
        for (int kt = 0; kt < 2; ++kt)
            wf[kt] = *(const llg*)(ws8 + 0 + (((kt * 8 + ut) * 64 + lane) << 3));
        const f4 bias = *(const f4*)(b0 + ut * 16 + quad * 4);
        #pragma unroll
        for (int pt = 0; pt < 2; ++pt) {
            f4 acc = bias;
            #pragma unroll
            for (int kt = 0; kt < 2; ++kt)
                acc = __builtin_amdgcn_mfma_f32_16x16x32_fp8_fp8(wf[kt], af[pt][kt], acc, 0, 0, 0);
            store_tile(acc, pt, ut);
        }
    }
    __builtin_amdgcn_s_barrier();

    // ---- L1, L2: bufH(K=128) -> bufH ----
    #pragma unroll
    for (int layer = 0; layer < 2; ++layer) {
        const unsigned char* wsl = ws8 + (layer == 0 ? 8192 : 24576);
        const float* bias_p = (layer == 0) ? b1 : b2;
        #pragma unroll
        for (int pt = 0; pt < 2; ++pt)
            #pragma unroll
            for (int kt = 0; kt < 4; ++kt)
                af[pt][kt] = *(const llg*)(bufH + pt * 16 * HSTRIDE_B + arow0 + kt * 32);
        #pragma unroll
        for (int ut = 0; ut < 8; ++ut) {
            llg wf[4];
            #pragma unroll
            for (int kt = 0; kt < 4; ++kt)
                wf[kt] = *(const llg*)(wsl + (((kt * 8 + ut) * 64 + lane) << 3));
            const f4 bias = *(const f4*)(bias_p + ut * 16 + quad * 4);
            #pragma unroll
            for (int pt = 0; pt < 2; ++pt) {
                f4 acc = bias;
                #pragma unroll
                for (int kt = 0; kt < 4; ++kt)
                    acc = __builtin_amdgcn_mfma_f32_16x16x32_fp8_fp8(wf[kt], af[pt][kt], acc, 0, 0, 0);
                store_tile(acc, pt, ut);
            }
        }
        __builtin_amdgcn_s_barrier();
    }

    // ---- L3: concat(bufH 128, fbuf 64) K=192 -> bufH ----
    #pragma unroll
    for (int pt = 0; pt < 2; ++pt) {
        #pragma unroll
        for (int kt = 0; kt < 4; ++kt)
            af[pt][kt] = *(const llg*)(bufH + pt * 16 * HSTRIDE_B + arow0 + kt * 32);
        #pragma unroll
        for (int kk = 0; kk < 2; ++kk)
            af[pt][4 + kk] = *(const llg*)(fbuf + pt * 16 * FSTRIDE_B + frow0 + kk * 32);
    }
    #pragma unroll
    for (int ut = 0; ut < 8; ++ut) {
        llg wf[6];
        #pragma unroll
        for (int kt = 0; kt < 6; ++kt)
            wf[kt] = *(const llg*)(ws8 + 40960 + (((kt * 8 + ut) * 64 + lane) << 3));
        const f4 bias = *(const f4*)(b3 + ut * 16 + quad * 4);
        #pragma unroll
        for (int pt = 0; pt < 2; ++pt) {
            f4 acc = bias;
            #pragma unroll
            for (int kt = 0; kt < 6; ++kt)
                acc = __builtin_amdgcn_mfma_f32_16x16x32_fp8_fp8(wf[kt], af[pt][kt], acc, 0, 0, 0);
            store_tile(acc, pt, ut);
        }
    }
    __builtin_amdgcn_s_barrier();

    // ---- output layer (K=128, N=3, wo scaled 2^13) + Rodrigues epilogue ----
    #pragma unroll
    for (int pt = 0; pt < 2; ++pt)
        #pragma unroll
        for (int kt = 0; kt < 4; ++kt)
            af[pt][kt] = *(const llg*)(bufH + pt * 16 * HSTRIDE_B + arow0 + kt * 32);
    llg wf[4];
    #pragma unroll
    for (int kt = 0; kt < 4; ++kt)
        wf[kt] = *(const llg*)(ws8 + 65536 + ((kt * 64 + lane) << 3));

    const float bo0 = bo[0], bo1 = bo[1], bo2 = bo[2];
    #pragma unroll
    for (int pt = 0; pt < 2; ++pt) {
        f4 acc = {0.f, 0.f, 0.f, 0.f};
        #pragma unroll
        for (int kt = 0; kt < 4; ++kt)
            acc = __builtin_amdgcn_mfma_f32_16x16x32_fp8_fp8(wf[kt], af[pt][kt], acc, 0, 0, 0);

        const int pp = pt * 16 + lm;
        const float* cst = (const float*)(fbuf + pp * FSTRIDE_B + 64);
        const float g1 = cst[0], g2 = cst[1], g3 = cst[2];
        const float r0 = acc[0] * WO_INV + bo0;
        const float r1 = acc[1] * WO_INV + bo1;
        const float r2 = acc[2] * WO_INV + bo2;
        const float theta = sqrtf(fmaf(r0, r0, fmaf(r1, r1, r2 * r2)) + 1e-12f);
        const float it = __builtin_amdgcn_rcpf(theta);
        const float e0 = r0 * it, e1 = r1 * it, e2 = r2 * it;
        const float a = sqrtf(fmaf(g1, g1, fmaf(g2, g2, g3 * g3)) + 1e-12f);
        const float ia = __builtin_amdgcn_rcpf(a);
        const float v0 = g1 * ia, v1 = g2 * ia, v2 = g3 * ia;
        float st, ct;
        __sincosf(theta, &st, &ct);
        const float cx = e1 * v2 - e2 * v1;
        const float cy = e2 * v0 - e0 * v2;
        const float cz = e0 * v1 - e1 * v0;
        const float om = (1.0f - ct) * (e0 * v0 + e1 * v1 + e2 * v2);
        if (quad == 0) {
            const int pid2 = pbase + pp;
            out[4 * B + pid2 * 3 + 0] = a * (ct * v0 + st * cx + om * e0);
            out[4 * B + pid2 * 3 + 1] = a * (ct * v1 + st * cy + om * e1);
            out[4 * B + pid2 * 3 + 2] = a * (ct * v2 + st * cz + om * e2);
        }
    }
}

extern "C" void kernel_launch(void* const* d_in, const int* in_sizes, int n_in,
                              void* d_out, int out_size, void* d_ws, size_t ws_size,
                              hipStream_t stream)
{
    const float* x    = (const float*)d_in[0];
    const float* grid = (const float*)d_in[1];
    const float* w0   = (const float*)d_in[2];
    const float* b0   = (const float*)d_in[3];
    const float* w1   = (const float*)d_in[4];
    const float* b1   = (const float*)d_in[5];
    const float* w2   = (const float*)d_in[6];
    const float* b2   = (const float*)d_in[7];
    const float* w3   = (const float*)d_in[8];
    const float* b3   = (const float*)d_in[9];
    const float* wo   = (const float*)d_in[10];
    const float* bo   = (const float*)d_in[11];
    float* out = (float*)d_out;
    unsigned char* ws8 = (unsigned char*)d_ws;
    unsigned short* dg = (unsigned short*)d_ws + DG_OFF_SH;

    const int B = in_sizes[0] / 3;        // 1,048,576
    const int fast = (ws_size >= WS_NEED) ? 1 : 0;
    const int nprep = fast ? (SWZ_BLOCKS + DG_BLOCKS) : SWZ_BLOCKS;
    prep<<<nprep, 256, 0, stream>>>(grid, w0, w1, w2, w3, wo, ws8, dg, fast);
    if (fast)
        voxmlp<true><<<B / 128, 256, 0, stream>>>(x, grid, ws8, dg, b0, b1, b2, b3, bo, out, B);
    else
        voxmlp<false><<<B / 128, 256, 0, stream>>>(x, grid, ws8, dg, b0, b1, b2, b3, bo, out, B);
}